// Round 1
// baseline (380.846 us; speedup 1.0000x reference)
//
#include <hip/hip_runtime.h>

#define NFEAT 2048
#define BATCH 16384

// One block per row. Stage the 2048-float row in LDS, gather from LDS.
__global__ __launch_bounds__(256) void swap_corrupt_kernel(
    const float* __restrict__ x,
    const int*   __restrict__ mask,
    const int*   __restrict__ perm,
    float*       __restrict__ out)
{
    __shared__ float row[NFEAT];

    const int r = blockIdx.x;
    const int t = threadIdx.x;
    const size_t base = (size_t)r * NFEAT;

    // Each thread loads 2 float4 (8 floats): elems [4t..4t+3] and [1024+4t..1024+4t+3]
    const float4* __restrict__ x4 = (const float4*)(x + base);
    float4 a = x4[t];
    float4 b = x4[t + 256];
    ((float4*)row)[t]       = a;
    ((float4*)row)[t + 256] = b;
    __syncthreads();

    const int4* __restrict__ m4 = (const int4*)(mask + base);
    const int4* __restrict__ p4 = (const int4*)(perm + base);
    float4* __restrict__ o4 = (float4*)(out + base);

    {
        int4 m = m4[t];
        int4 p = p4[t];
        float4 o;
        o.x = m.x ? row[p.x] : a.x;
        o.y = m.y ? row[p.y] : a.y;
        o.z = m.z ? row[p.z] : a.z;
        o.w = m.w ? row[p.w] : a.w;
        o4[t] = o;
    }
    {
        int4 m = m4[t + 256];
        int4 p = p4[t + 256];
        float4 o;
        o.x = m.x ? row[p.x] : b.x;
        o.y = m.y ? row[p.y] : b.y;
        o.z = m.z ? row[p.z] : b.z;
        o.w = m.w ? row[p.w] : b.w;
        o4[t + 256] = o;
    }
}

extern "C" void kernel_launch(void* const* d_in, const int* in_sizes, int n_in,
                              void* d_out, int out_size, void* d_ws, size_t ws_size,
                              hipStream_t stream) {
    const float* x    = (const float*)d_in[0];
    const int*   mask = (const int*)d_in[1];
    const int*   perm = (const int*)d_in[2];
    float*       out  = (float*)d_out;

    swap_corrupt_kernel<<<dim3(BATCH), dim3(256), 0, stream>>>(x, mask, perm, out);
}